// Round 1
// baseline (534.622 us; speedup 1.0000x reference)
//
#include <hip/hip_runtime.h>
#include <math.h>

// ---------------- constants (match reference) ----------------
// H=4 heads, C=128 channels/head, D=128, HC=512, slope=0.2

__device__ __forceinline__ float lrelu(float v) { return v >= 0.0f ? v : 0.2f * v; }

// ---------------- GEMM: h[N,512] = x[N,128] @ W[128,512] (f32 vector) ----------------
__global__ __launch_bounds__(256, 2) void gemm_xw(const float* __restrict__ x,
                                                  const float* __restrict__ W,
                                                  float* __restrict__ hmat, int N) {
    __shared__ float As[64][132];   // x tile, rows padded to 132 floats (528B, 16B-aligned)
    __shared__ float Bs[128][64];   // W tile
    const int row0 = blockIdx.x * 64;
    const int col0 = blockIdx.y * 64;
    const int t = threadIdx.x;

    // load x tile: 64 rows x 128 cols = 2048 float4, 8 per thread
    {
        const float4* xv = (const float4*)x;
        #pragma unroll
        for (int i = 0; i < 8; i++) {
            int f = t + 256 * i;
            int m = f >> 5;        // 32 float4 per row
            int k4 = f & 31;
            float4 v = make_float4(0.f, 0.f, 0.f, 0.f);
            int row = row0 + m;
            if (row < N) v = xv[row * 32 + k4];
            *(float4*)&As[m][k4 * 4] = v;
        }
        const float4* wv = (const float4*)W;  // W row = 512 floats = 128 float4
        #pragma unroll
        for (int i = 0; i < 8; i++) {
            int f = t + 256 * i;
            int k = f >> 4;        // 16 float4 per tile row
            int n4 = f & 15;
            float4 v = wv[k * 128 + (col0 >> 2) + n4];
            *(float4*)&Bs[k][n4 * 4] = v;
        }
    }
    __syncthreads();

    const int tx = t & 15, ty = t >> 4;
    float acc[4][4];
    #pragma unroll
    for (int i = 0; i < 4; i++)
        #pragma unroll
        for (int j = 0; j < 4; j++) acc[i][j] = 0.f;

    for (int k0 = 0; k0 < 128; k0 += 4) {
        float4 a[4], b[4];
        #pragma unroll
        for (int i = 0; i < 4; i++) a[i] = *(const float4*)&As[ty * 4 + i][k0];
        #pragma unroll
        for (int kk = 0; kk < 4; kk++) b[kk] = *(const float4*)&Bs[k0 + kk][tx * 4];
        #pragma unroll
        for (int kk = 0; kk < 4; kk++) {
            #pragma unroll
            for (int i = 0; i < 4; i++) {
                float av = ((const float*)&a[i])[kk];
                acc[i][0] = fmaf(av, b[kk].x, acc[i][0]);
                acc[i][1] = fmaf(av, b[kk].y, acc[i][1]);
                acc[i][2] = fmaf(av, b[kk].z, acc[i][2]);
                acc[i][3] = fmaf(av, b[kk].w, acc[i][3]);
            }
        }
    }

    #pragma unroll
    for (int i = 0; i < 4; i++) {
        int row = row0 + ty * 4 + i;
        if (row < N) {
            float4 v = make_float4(acc[i][0], acc[i][1], acc[i][2], acc[i][3]);
            *(float4*)&hmat[row * 512 + col0 + tx * 4] = v;
        }
    }
}

// ---------------- attention coefficients: a_src[n,h] = dot(h[n,h,:], att_src[h,:]) ----------------
__global__ __launch_bounds__(256) void attn_coef(const float* __restrict__ hmat,
                                                 const float* __restrict__ att_src,
                                                 const float* __restrict__ att_dst,
                                                 float* __restrict__ a_src4,
                                                 float* __restrict__ a_dst4, int N) {
    int wid = (blockIdx.x * 256 + threadIdx.x) >> 6;
    int lane = threadIdx.x & 63;
    if (wid >= N) return;
    int hd = lane >> 4;
    int c0 = (lane & 15) * 8;

    const float* hp = &hmat[wid * 512 + lane * 8];
    float4 h0 = *(const float4*)hp;
    float4 h1 = *(const float4*)(hp + 4);
    const float* sp = &att_src[hd * 128 + c0];
    const float* dp = &att_dst[hd * 128 + c0];
    float4 s0 = *(const float4*)sp, s1 = *(const float4*)(sp + 4);
    float4 d0 = *(const float4*)dp, d1 = *(const float4*)(dp + 4);

    float ps = h0.x * s0.x + h0.y * s0.y + h0.z * s0.z + h0.w * s0.w +
               h1.x * s1.x + h1.y * s1.y + h1.z * s1.z + h1.w * s1.w;
    float pd = h0.x * d0.x + h0.y * d0.y + h0.z * d0.z + h0.w * d0.w +
               h1.x * d1.x + h1.y * d1.y + h1.z * d1.z + h1.w * d1.w;

    #pragma unroll
    for (int off = 1; off < 16; off <<= 1) {
        ps += __shfl_xor(ps, off);
        pd += __shfl_xor(pd, off);
    }
    if ((lane & 15) == 0) {
        a_src4[wid * 4 + hd] = ps;
        a_dst4[wid * 4 + hd] = pd;
    }
}

// ---------------- CSR build ----------------
__global__ void count_deg(const int* __restrict__ dst, int E, int* deg) {
    int i = blockIdx.x * 256 + threadIdx.x;
    if (i < E) atomicAdd(&deg[dst[i]], 1);
}

__global__ __launch_bounds__(1024) void scan_deg(const int* __restrict__ deg,
                                                 int* __restrict__ rowstart, int N) {
    __shared__ int sm[1024];
    __shared__ int carry_s;
    int t = threadIdx.x;
    if (t == 0) carry_s = 0;
    __syncthreads();
    for (int base = 0; base < N; base += 1024) {
        int v = (base + t < N) ? deg[base + t] : 0;
        sm[t] = v;
        __syncthreads();
        int x = v;
        for (int off = 1; off < 1024; off <<= 1) {
            int y = (t >= off) ? sm[t - off] : 0;
            __syncthreads();
            x += y;
            sm[t] = x;
            __syncthreads();
        }
        int carry = carry_s;
        if (base + t < N) rowstart[base + t] = carry + x - v;  // exclusive
        __syncthreads();
        if (t == 1023) carry_s = carry + x;
        __syncthreads();
    }
}

__global__ void fill_csr(const int* __restrict__ src, const int* __restrict__ dst, int E,
                         int* cursor, int* __restrict__ csr_src) {
    int i = blockIdx.x * 256 + threadIdx.x;
    if (i < E) {
        int d = dst[i];
        int pos = atomicAdd(&cursor[d], 1);
        csr_src[pos] = src[i];
    }
}

// ---------------- aggregation: one wave per dst node ----------------
__global__ __launch_bounds__(256) void aggregate(const float* __restrict__ hmat,
                                                 const float* __restrict__ a_src4,
                                                 const float* __restrict__ a_dst4,
                                                 const int* __restrict__ rowstart,
                                                 const int* __restrict__ deg,
                                                 const int* __restrict__ csr_src,
                                                 const float* __restrict__ bias,
                                                 float* __restrict__ out, int N) {
    int wid = (blockIdx.x * 256 + threadIdx.x) >> 6;
    int lane = threadIdx.x & 63;
    if (wid >= N) return;
    const int n = wid;
    const int myhd = lane >> 4;

    float ad4[4], es[4];
    {
        float4 td = *(const float4*)&a_dst4[n * 4];
        ad4[0] = td.x; ad4[1] = td.y; ad4[2] = td.z; ad4[3] = td.w;
        float4 ts = *(const float4*)&a_src4[n * 4];
        es[0] = lrelu(ts.x + ad4[0]);
        es[1] = lrelu(ts.y + ad4[1]);
        es[2] = lrelu(ts.z + ad4[2]);
        es[3] = lrelu(ts.w + ad4[3]);
    }
    const int rs = rowstart[n];
    const int dg = deg[n];

    // pass A: per-head max (self-loop logit as init)
    float mx[4] = {es[0], es[1], es[2], es[3]};
    for (int e = lane; e < dg; e += 64) {
        int s = csr_src[rs + e];
        float4 a = *(const float4*)&a_src4[s * 4];
        mx[0] = fmaxf(mx[0], lrelu(a.x + ad4[0]));
        mx[1] = fmaxf(mx[1], lrelu(a.y + ad4[1]));
        mx[2] = fmaxf(mx[2], lrelu(a.z + ad4[2]));
        mx[3] = fmaxf(mx[3], lrelu(a.w + ad4[3]));
    }
    #pragma unroll
    for (int off = 1; off < 64; off <<= 1) {
        mx[0] = fmaxf(mx[0], __shfl_xor(mx[0], off));
        mx[1] = fmaxf(mx[1], __shfl_xor(mx[1], off));
        mx[2] = fmaxf(mx[2], __shfl_xor(mx[2], off));
        mx[3] = fmaxf(mx[3], __shfl_xor(mx[3], off));
    }

    // pass B: accumulate
    float ssum[4] = {0.f, 0.f, 0.f, 0.f};
    float acc[8] = {0.f, 0.f, 0.f, 0.f, 0.f, 0.f, 0.f, 0.f};

    // self edge
    {
        float p[4];
        #pragma unroll
        for (int k = 0; k < 4; k++) { p[k] = __expf(es[k] - mx[k]); ssum[k] += p[k]; }
        const float* hp = &hmat[n * 512 + lane * 8];
        float4 v0 = *(const float4*)hp;
        float4 v1 = *(const float4*)(hp + 4);
        float ph = p[myhd];
        acc[0] = fmaf(ph, v0.x, acc[0]); acc[1] = fmaf(ph, v0.y, acc[1]);
        acc[2] = fmaf(ph, v0.z, acc[2]); acc[3] = fmaf(ph, v0.w, acc[3]);
        acc[4] = fmaf(ph, v1.x, acc[4]); acc[5] = fmaf(ph, v1.y, acc[5]);
        acc[6] = fmaf(ph, v1.z, acc[6]); acc[7] = fmaf(ph, v1.w, acc[7]);
    }

    for (int e = 0; e < dg; e++) {
        int s = csr_src[rs + e];
        float4 a = *(const float4*)&a_src4[s * 4];
        float p0 = __expf(lrelu(a.x + ad4[0]) - mx[0]);
        float p1 = __expf(lrelu(a.y + ad4[1]) - mx[1]);
        float p2 = __expf(lrelu(a.z + ad4[2]) - mx[2]);
        float p3 = __expf(lrelu(a.w + ad4[3]) - mx[3]);
        ssum[0] += p0; ssum[1] += p1; ssum[2] += p2; ssum[3] += p3;
        float ph = myhd == 0 ? p0 : (myhd == 1 ? p1 : (myhd == 2 ? p2 : p3));
        const float* hp = &hmat[s * 512 + lane * 8];
        float4 v0 = *(const float4*)hp;
        float4 v1 = *(const float4*)(hp + 4);
        acc[0] = fmaf(ph, v0.x, acc[0]); acc[1] = fmaf(ph, v0.y, acc[1]);
        acc[2] = fmaf(ph, v0.z, acc[2]); acc[3] = fmaf(ph, v0.w, acc[3]);
        acc[4] = fmaf(ph, v1.x, acc[4]); acc[5] = fmaf(ph, v1.y, acc[5]);
        acc[6] = fmaf(ph, v1.z, acc[6]); acc[7] = fmaf(ph, v1.w, acc[7]);
    }

    // finalize: acc/(H*sum[head]) then reduce over the 4 head groups
    float inv = 1.0f / (4.0f * ssum[myhd]);
    #pragma unroll
    for (int j = 0; j < 8; j++) acc[j] *= inv;
    #pragma unroll
    for (int off = 16; off < 64; off <<= 1) {
        #pragma unroll
        for (int j = 0; j < 8; j++) acc[j] += __shfl_xor(acc[j], off);
    }
    if (lane < 16) {
        const float* bp = &bias[lane * 8];
        float4 b0 = *(const float4*)bp;
        float4 b1 = *(const float4*)(bp + 4);
        float4 o0 = make_float4(acc[0] + b0.x, acc[1] + b0.y, acc[2] + b0.z, acc[3] + b0.w);
        float4 o1 = make_float4(acc[4] + b1.x, acc[5] + b1.y, acc[6] + b1.z, acc[7] + b1.w);
        float* op = &out[n * 128 + lane * 8];
        *(float4*)op = o0;
        *(float4*)(op + 4) = o1;
    }
}

// ---------------- launcher ----------------
extern "C" void kernel_launch(void* const* d_in, const int* in_sizes, int n_in,
                              void* d_out, int out_size, void* d_ws, size_t ws_size,
                              hipStream_t stream) {
    const float* x = (const float*)d_in[0];
    const int* ei = (const int*)d_in[1];
    const float* W = (const float*)d_in[2];
    const float* att_src = (const float*)d_in[3];
    const float* att_dst = (const float*)d_in[4];
    const float* bias = (const float*)d_in[5];
    float* out = (float*)d_out;

    const int N = in_sizes[0] / 128;
    const int E = in_sizes[1] / 2;
    const int* esrc = ei;
    const int* edst = ei + E;

    char* ws = (char*)d_ws;
    size_t off = 0;
    auto alloc = [&](size_t bytes) {
        void* p = ws + off;
        off = (off + bytes + 511) & ~(size_t)511;
        return p;
    };
    float* h = (float*)alloc((size_t)N * 512 * 4);
    float* a_src4 = (float*)alloc((size_t)N * 16);
    float* a_dst4 = (float*)alloc((size_t)N * 16);
    int* deg = (int*)alloc((size_t)N * 4);
    int* rowstart = (int*)alloc((size_t)N * 4);
    int* cursor = (int*)alloc((size_t)N * 4);
    int* csr_src = (int*)alloc((size_t)E * 4);

    hipMemsetAsync(deg, 0, (size_t)N * 4, stream);

    dim3 gg((N + 63) / 64, 8);
    gemm_xw<<<gg, 256, 0, stream>>>(x, W, h, N);

    int nwave_blocks = (N * 64 + 255) / 256;
    attn_coef<<<nwave_blocks, 256, 0, stream>>>(h, att_src, att_dst, a_src4, a_dst4, N);

    int eblocks = (E + 255) / 256;
    count_deg<<<eblocks, 256, 0, stream>>>(edst, E, deg);
    scan_deg<<<1, 1024, 0, stream>>>(deg, rowstart, N);
    hipMemcpyAsync(cursor, rowstart, (size_t)N * 4, hipMemcpyDeviceToDevice, stream);
    fill_csr<<<eblocks, 256, 0, stream>>>(esrc, edst, E, cursor, csr_src);

    aggregate<<<nwave_blocks, 256, 0, stream>>>(h, a_src4, a_dst4, rowstart, deg, csr_src,
                                                bias, out, N);
}

// Round 2
// 306.616 us; speedup vs baseline: 1.7436x; 1.7436x over previous
//
#include <hip/hip_runtime.h>
#include <math.h>

typedef __attribute__((ext_vector_type(8))) short bf16x8;
typedef __attribute__((ext_vector_type(4))) float f32x4;

__device__ __forceinline__ float lrelu(float v) { return v >= 0.0f ? v : 0.2f * v; }

__device__ __forceinline__ unsigned short f2bf(float f) {
    unsigned u = __builtin_bit_cast(unsigned, f);
    unsigned r = (u + 0x7fffu + ((u >> 16) & 1u)) >> 16;
    return (unsigned short)r;
}
__device__ __forceinline__ float bflo(unsigned u) { return __builtin_bit_cast(float, u << 16); }
__device__ __forceinline__ float bfhi(unsigned u) { return __builtin_bit_cast(float, u & 0xffff0000u); }

// ---------------- prep: x -> bf16, W -> bf16 transposed ----------------
__global__ __launch_bounds__(256) void convert_x(const float* __restrict__ x,
                                                 unsigned short* __restrict__ xb, int total8) {
    int i = blockIdx.x * 256 + threadIdx.x;
    if (i >= total8) return;
    const float4* xv = (const float4*)x;
    float4 v0 = xv[i * 2], v1 = xv[i * 2 + 1];
    uint4 o;
    o.x = (unsigned)f2bf(v0.x) | ((unsigned)f2bf(v0.y) << 16);
    o.y = (unsigned)f2bf(v0.z) | ((unsigned)f2bf(v0.w) << 16);
    o.z = (unsigned)f2bf(v1.x) | ((unsigned)f2bf(v1.y) << 16);
    o.w = (unsigned)f2bf(v1.z) | ((unsigned)f2bf(v1.w) << 16);
    ((uint4*)xb)[i] = o;
}

__global__ __launch_bounds__(256) void transpose_w(const float* __restrict__ W,
                                                   unsigned short* __restrict__ Wt) {
    int id = blockIdx.x * 256 + threadIdx.x;  // 65536 total
    int k = id >> 9, n = id & 511;            // coalesced read of W[k][n]
    Wt[n * 128 + k] = f2bf(W[k * 512 + n]);
}

// ---------------- GEMM (bf16 MFMA): h2[N,512]=xb@W, + fused attn coefs ----------------
#define LDA 136  // halves per LDS row (272B, 16B aligned, spreads banks)

__global__ __launch_bounds__(256, 2) void gemm_mfma(const unsigned short* __restrict__ xb,
                                                    const unsigned short* __restrict__ Wt,
                                                    const float* __restrict__ att_src,
                                                    const float* __restrict__ att_dst,
                                                    unsigned short* __restrict__ h2,
                                                    float* __restrict__ a_src4,
                                                    float* __restrict__ a_dst4, int N) {
    __shared__ unsigned short As[128 * LDA];
    __shared__ unsigned short Bs[128 * LDA];
    __shared__ float Ps[128][2][2];  // [local row][wc][src=0/dst=1]

    const int brow = blockIdx.x * 128;
    const int hd = blockIdx.y;          // column tile == head (128 cols)
    const int bcol = hd * 128;
    const int t = threadIdx.x;

    // stage A (x rows) and B (Wt rows = output cols), 16B per thread per iter
    #pragma unroll
    for (int i = 0; i < 8; i++) {
        int idx = t + 256 * i;
        int r = idx >> 4, c = idx & 15;
        uint4 v = make_uint4(0u, 0u, 0u, 0u);
        int row = brow + r;
        if (row < N) v = *(const uint4*)&xb[row * 128 + c * 8];
        *(uint4*)&As[r * LDA + c * 8] = v;
    }
    #pragma unroll
    for (int i = 0; i < 8; i++) {
        int idx = t + 256 * i;
        int r = idx >> 4, c = idx & 15;
        uint4 v = *(const uint4*)&Wt[(bcol + r) * 128 + c * 8];
        *(uint4*)&Bs[r * LDA + c * 8] = v;
    }
    __syncthreads();

    const int wid = t >> 6, l = t & 63;
    const int wr = wid >> 1, wc = wid & 1;   // wave quadrant (64x64)
    const int r = l & 15, g = l >> 4;

    f32x4 zero4 = {0.f, 0.f, 0.f, 0.f};
    f32x4 acc[4][4];
    #pragma unroll
    for (int m = 0; m < 4; m++)
        #pragma unroll
        for (int n = 0; n < 4; n++) acc[m][n] = zero4;

    #pragma unroll
    for (int ks = 0; ks < 4; ks++) {        // K = 128 = 4 x 32
        bf16x8 a[4], b[4];
        #pragma unroll
        for (int m = 0; m < 4; m++)
            a[m] = *(const bf16x8*)&As[(wr * 64 + m * 16 + r) * LDA + ks * 32 + g * 8];
        #pragma unroll
        for (int n = 0; n < 4; n++)
            b[n] = *(const bf16x8*)&Bs[(wc * 64 + n * 16 + r) * LDA + ks * 32 + g * 8];
        #pragma unroll
        for (int m = 0; m < 4; m++)
            #pragma unroll
            for (int n = 0; n < 4; n++)
                acc[m][n] = __builtin_amdgcn_mfma_f32_16x16x32_bf16(a[m], b[n], acc[m][n], 0, 0, 0);
    }

    // write h2 (bf16). D layout: col = lane&15, row = (lane>>4)*4 + reg
    #pragma unroll
    for (int m = 0; m < 4; m++) {
        #pragma unroll
        for (int j = 0; j < 4; j++) {
            int row = brow + wr * 64 + m * 16 + g * 4 + j;
            if (row < N) {
                #pragma unroll
                for (int n = 0; n < 4; n++) {
                    int col = bcol + wc * 64 + n * 16 + r;
                    h2[(size_t)row * 512 + col] = f2bf(acc[m][n][j]);
                }
            }
        }
    }

    // fused attention coefficients from f32 accumulators
    float as_att[4], ad_att[4];
    #pragma unroll
    for (int n = 0; n < 4; n++) {
        int col = wc * 64 + n * 16 + r;
        as_att[n] = att_src[hd * 128 + col];
        ad_att[n] = att_dst[hd * 128 + col];
    }
    #pragma unroll
    for (int m = 0; m < 4; m++) {
        #pragma unroll
        for (int j = 0; j < 4; j++) {
            float ps = acc[m][0][j] * as_att[0] + acc[m][1][j] * as_att[1] +
                       acc[m][2][j] * as_att[2] + acc[m][3][j] * as_att[3];
            float pd = acc[m][0][j] * ad_att[0] + acc[m][1][j] * ad_att[1] +
                       acc[m][2][j] * ad_att[2] + acc[m][3][j] * ad_att[3];
            #pragma unroll
            for (int off = 1; off < 16; off <<= 1) {
                ps += __shfl_xor(ps, off);
                pd += __shfl_xor(pd, off);
            }
            if (r == 0) {
                int lrow = wr * 64 + m * 16 + g * 4 + j;
                Ps[lrow][wc][0] = ps;
                Ps[lrow][wc][1] = pd;
            }
        }
    }
    __syncthreads();
    if (t < 128) {
        int row = brow + t;
        if (row < N) {
            a_src4[row * 4 + hd] = Ps[t][0][0] + Ps[t][1][0];
            a_dst4[row * 4 + hd] = Ps[t][0][1] + Ps[t][1][1];
        }
    }
}

// ---------------- CSR build ----------------
__global__ void count_deg(const int* __restrict__ dst, int E, int* deg) {
    int i = blockIdx.x * 256 + threadIdx.x;
    if (i < E) atomicAdd(&deg[dst[i]], 1);
}

__global__ __launch_bounds__(1024) void scan_deg(const int* __restrict__ deg,
                                                 int* __restrict__ rowstart, int N) {
    __shared__ int wsum[16];
    __shared__ int carry_s;
    const int t = threadIdx.x, w = t >> 6, l = t & 63;
    if (t == 0) carry_s = 0;
    __syncthreads();
    for (int base = 0; base < N; base += 1024) {
        int v = (base + t < N) ? deg[base + t] : 0;
        int x = v;
        #pragma unroll
        for (int off = 1; off < 64; off <<= 1) {
            int y = __shfl_up(x, off);
            if (l >= off) x += y;
        }
        if (l == 63) wsum[w] = x;
        __syncthreads();
        if (t < 16) {
            int s = wsum[t];
            #pragma unroll
            for (int off = 1; off < 16; off <<= 1) {
                int y = __shfl_up(s, off);
                if (t >= off) s += y;
            }
            wsum[t] = s;  // inclusive scan of wave sums
        }
        __syncthreads();
        int carry = carry_s;
        int tot = wsum[15];
        int woff = (w > 0) ? wsum[w - 1] : 0;
        if (base + t < N) rowstart[base + t] = carry + woff + x - v;  // exclusive
        __syncthreads();
        if (t == 0) carry_s = carry + tot;
        // next iter's first __syncthreads orders this write before wsum reuse reads;
        // wsum rewrite (l==63) races only with carry_s write target? no: distinct addrs.
        __syncthreads();
    }
}

__global__ void fill_csr(const int* __restrict__ src, const int* __restrict__ dst, int E,
                         int* cursor, int* __restrict__ csr_src) {
    int i = blockIdx.x * 256 + threadIdx.x;
    if (i < E) {
        int d = dst[i];
        int pos = atomicAdd(&cursor[d], 1);
        csr_src[pos] = src[i];
    }
}

// ---------------- aggregation: one wave per dst node, single pass, bf16 gathers ----------------
#define ACCUM(p, v)                                                            \
    {                                                                          \
        acc[0] = fmaf(p, bflo(v.x), acc[0]);                                   \
        acc[1] = fmaf(p, bfhi(v.x), acc[1]);                                   \
        acc[2] = fmaf(p, bflo(v.y), acc[2]);                                   \
        acc[3] = fmaf(p, bfhi(v.y), acc[3]);                                   \
        acc[4] = fmaf(p, bflo(v.z), acc[4]);                                   \
        acc[5] = fmaf(p, bfhi(v.z), acc[5]);                                   \
        acc[6] = fmaf(p, bflo(v.w), acc[6]);                                   \
        acc[7] = fmaf(p, bfhi(v.w), acc[7]);                                   \
    }

__global__ __launch_bounds__(256) void aggregate(const unsigned short* __restrict__ h2,
                                                 const float* __restrict__ a_src4,
                                                 const float* __restrict__ a_dst4,
                                                 const int* __restrict__ rowstart,
                                                 const int* __restrict__ deg,
                                                 const int* __restrict__ csr_src,
                                                 const float* __restrict__ bias,
                                                 float* __restrict__ out, int N) {
    int wid = (blockIdx.x * 256 + threadIdx.x) >> 6;
    int l = threadIdx.x & 63;
    if (wid >= N) return;
    const int n = wid;
    const int hd = l >> 4;

    const float ad_my = a_dst4[n * 4 + hd];
    float acc[8];
    float ssum;
    {   // self loop
        float p = __expf(lrelu(a_src4[n * 4 + hd] + ad_my));
        ssum = p;
        uint4 v = *(const uint4*)&h2[(size_t)n * 512 + l * 8];
        acc[0] = p * bflo(v.x); acc[1] = p * bfhi(v.x);
        acc[2] = p * bflo(v.y); acc[3] = p * bfhi(v.y);
        acc[4] = p * bflo(v.z); acc[5] = p * bfhi(v.z);
        acc[6] = p * bflo(v.w); acc[7] = p * bfhi(v.w);
    }

    const int rs = rowstart[n];
    const int dg = deg[n];
    int e = 0;
    for (; e + 4 <= dg; e += 4) {
        int s0 = csr_src[rs + e + 0];
        int s1 = csr_src[rs + e + 1];
        int s2 = csr_src[rs + e + 2];
        int s3 = csr_src[rs + e + 3];
        float l0 = a_src4[s0 * 4 + hd];
        float l1 = a_src4[s1 * 4 + hd];
        float l2 = a_src4[s2 * 4 + hd];
        float l3 = a_src4[s3 * 4 + hd];
        uint4 v0 = *(const uint4*)&h2[(size_t)s0 * 512 + l * 8];
        uint4 v1 = *(const uint4*)&h2[(size_t)s1 * 512 + l * 8];
        uint4 v2 = *(const uint4*)&h2[(size_t)s2 * 512 + l * 8];
        uint4 v3 = *(const uint4*)&h2[(size_t)s3 * 512 + l * 8];
        float p0 = __expf(lrelu(l0 + ad_my));
        float p1 = __expf(lrelu(l1 + ad_my));
        float p2 = __expf(lrelu(l2 + ad_my));
        float p3 = __expf(lrelu(l3 + ad_my));
        ssum += p0 + p1 + p2 + p3;
        ACCUM(p0, v0);
        ACCUM(p1, v1);
        ACCUM(p2, v2);
        ACCUM(p3, v3);
    }
    for (; e < dg; e++) {
        int s = csr_src[rs + e];
        float le = a_src4[s * 4 + hd];
        uint4 v = *(const uint4*)&h2[(size_t)s * 512 + l * 8];
        float p = __expf(lrelu(le + ad_my));
        ssum += p;
        ACCUM(p, v);
    }

    float inv = 1.0f / (4.0f * ssum);
    #pragma unroll
    for (int j = 0; j < 8; j++) acc[j] *= inv;
    #pragma unroll
    for (int off = 16; off < 64; off <<= 1) {
        #pragma unroll
        for (int j = 0; j < 8; j++) acc[j] += __shfl_xor(acc[j], off);
    }
    if (l < 16) {
        const float* bp = &bias[l * 8];
        float4 b0 = *(const float4*)bp;
        float4 b1 = *(const float4*)(bp + 4);
        float* op = &out[(size_t)n * 128 + l * 8];
        *(float4*)op = make_float4(acc[0] + b0.x, acc[1] + b0.y, acc[2] + b0.z, acc[3] + b0.w);
        *(float4*)(op + 4) = make_float4(acc[4] + b1.x, acc[5] + b1.y, acc[6] + b1.z, acc[7] + b1.w);
    }
}

// ---------------- launcher ----------------
extern "C" void kernel_launch(void* const* d_in, const int* in_sizes, int n_in,
                              void* d_out, int out_size, void* d_ws, size_t ws_size,
                              hipStream_t stream) {
    const float* x = (const float*)d_in[0];
    const int* ei = (const int*)d_in[1];
    const float* W = (const float*)d_in[2];
    const float* att_src = (const float*)d_in[3];
    const float* att_dst = (const float*)d_in[4];
    const float* bias = (const float*)d_in[5];
    float* out = (float*)d_out;

    const int N = in_sizes[0] / 128;
    const int E = in_sizes[1] / 2;
    const int* esrc = ei;
    const int* edst = ei + E;

    char* ws = (char*)d_ws;
    size_t off = 0;
    auto alloc = [&](size_t bytes) {
        void* p = ws + off;
        off = (off + bytes + 511) & ~(size_t)511;
        return p;
    };
    unsigned short* h2 = (unsigned short*)alloc((size_t)N * 512 * 2);
    unsigned short* xb = (unsigned short*)alloc((size_t)N * 128 * 2);
    unsigned short* Wt = (unsigned short*)alloc((size_t)512 * 128 * 2);
    float* a_src4 = (float*)alloc((size_t)N * 16);
    float* a_dst4 = (float*)alloc((size_t)N * 16);
    int* deg = (int*)alloc((size_t)N * 4);
    int* rowstart = (int*)alloc((size_t)N * 4);
    int* cursor = (int*)alloc((size_t)N * 4);
    int* csr_src = (int*)alloc((size_t)E * 4);

    hipMemsetAsync(deg, 0, (size_t)N * 4, stream);

    int total8 = N * 16;  // N*128/8
    convert_x<<<(total8 + 255) / 256, 256, 0, stream>>>(x, xb, total8);
    transpose_w<<<256, 256, 0, stream>>>(W, Wt);

    dim3 gg((N + 127) / 128, 4);
    gemm_mfma<<<gg, 256, 0, stream>>>(xb, Wt, att_src, att_dst, h2, a_src4, a_dst4, N);

    int eblocks = (E + 255) / 256;
    count_deg<<<eblocks, 256, 0, stream>>>(edst, E, deg);
    scan_deg<<<1, 1024, 0, stream>>>(deg, rowstart, N);
    hipMemcpyAsync(cursor, rowstart, (size_t)N * 4, hipMemcpyDeviceToDevice, stream);
    fill_csr<<<eblocks, 256, 0, stream>>>(esrc, edst, E, cursor, csr_src);

    int nwave_blocks = (N * 64 + 255) / 256;
    aggregate<<<nwave_blocks, 256, 0, stream>>>(h2, a_src4, a_dst4, rowstart, deg, csr_src,
                                                bias, out, N);
}